// Round 1
// baseline (335.677 us; speedup 1.0000x reference)
//
#include <hip/hip_runtime.h>

typedef unsigned short u16;
typedef __attribute__((ext_vector_type(8))) short bf16x8;   // 8 bf16 (4 VGPRs)
typedef __attribute__((ext_vector_type(4))) float f32x4;

#define HEADS 12
#define HDIM  64
#define EMBED 768
#define TD    2304
#define SEQ   1024
#define MTOK  8192

// round-to-nearest-even f32 -> bf16
__device__ __forceinline__ u16 f2bf(float f) {
  union { float f; unsigned u; } x; x.f = f;
  unsigned r = x.u + 0x7fffu + ((x.u >> 16) & 1u);
  return (u16)(r >> 16);
}

__global__ void cast_kernel(const float* __restrict__ src, u16* __restrict__ dst, int n4) {
  int i = blockIdx.x * blockDim.x + threadIdx.x;
  int st = gridDim.x * blockDim.x;
  for (; i < n4; i += st) {
    float4 v = reinterpret_cast<const float4*>(src)[i];
    ushort4 o;
    o.x = f2bf(v.x); o.y = f2bf(v.y); o.z = f2bf(v.z); o.w = f2bf(v.w);
    reinterpret_cast<ushort4*>(dst)[i] = o;
  }
}

__device__ __forceinline__ void gload_lds16(const u16* g, u16* l) {
  __builtin_amdgcn_global_load_lds(
      (const __attribute__((address_space(1))) unsigned*)g,
      (__attribute__((address_space(3))) unsigned*)l, 16, 0, 0);
}

// C[M][N] = A[M][K] @ B[N][K]^T (+ bias[N]); A,B bf16; out bf16 or f32.
// 128x128 tile, BK=32, 256 threads = 4 waves (2x2), each wave 4x4 16x16 frags.
template <bool OUT_BF16, bool HAS_BIAS>
__global__ __launch_bounds__(256) void gemm_bt(const u16* __restrict__ A,
                                               const u16* __restrict__ B,
                                               const float* __restrict__ bias,
                                               void* __restrict__ Cv, int K) {
  __shared__ u16 As[128 * 32];
  __shared__ u16 Bs[128 * 32];
  const int tid  = threadIdx.x;
  const int wave = tid >> 6, lane = tid & 63;
  const int wr = wave >> 1, wc = wave & 1;
  const int lr = lane & 15, lk = (lane >> 4) * 8;
  const int Ndim = gridDim.y * 128;
  const int srow = lane >> 2;          // staging row within 16-row chunk
  const int scol = (lane & 3) * 8;     // staging col (elements)

  const u16* Ag = A + (size_t)(blockIdx.x * 128) * K;
  const u16* Bg = B + (size_t)(blockIdx.y * 128) * K;

  f32x4 acc[4][4];
#pragma unroll
  for (int m = 0; m < 4; ++m)
#pragma unroll
    for (int n = 0; n < 4; ++n) acc[m][n] = 0.f;

  for (int kt = 0; kt < K; kt += 32) {
#pragma unroll
    for (int c = 0; c < 2; ++c) {
      int slot = wave * 2 + c;               // 0..7, wave-uniform
      int row  = slot * 16 + srow;
      gload_lds16(Ag + (size_t)row * K + kt + scol, &As[slot * 512]);
      gload_lds16(Bg + (size_t)row * K + kt + scol, &Bs[slot * 512]);
    }
    __syncthreads();
    bf16x8 af[4], bfr[4];
#pragma unroll
    for (int m = 0; m < 4; ++m)
      af[m] = *reinterpret_cast<const bf16x8*>(&As[(wr * 64 + m * 16 + lr) * 32 + lk]);
#pragma unroll
    for (int n = 0; n < 4; ++n)
      bfr[n] = *reinterpret_cast<const bf16x8*>(&Bs[(wc * 64 + n * 16 + lr) * 32 + lk]);
#pragma unroll
    for (int m = 0; m < 4; ++m)
#pragma unroll
      for (int n = 0; n < 4; ++n)
        acc[m][n] = __builtin_amdgcn_mfma_f32_16x16x32_bf16(af[m], bfr[n], acc[m][n], 0, 0, 0);
    __syncthreads();
  }

  const int row0 = blockIdx.x * 128 + wr * 64 + (lane >> 4) * 4;
  const int col0 = blockIdx.y * 128 + wc * 64 + lr;
#pragma unroll
  for (int m = 0; m < 4; ++m)
#pragma unroll
    for (int n = 0; n < 4; ++n) {
      int col = col0 + n * 16;
      float bv = HAS_BIAS ? bias[col] : 0.f;
#pragma unroll
      for (int j = 0; j < 4; ++j) {
        int row = row0 + m * 16 + j;
        float v = acc[m][n][j] + bv;
        if (OUT_BF16) ((u16*)Cv)[(size_t)row * Ndim + col] = f2bf(v);
        else          ((float*)Cv)[(size_t)row * Ndim + col] = v;
      }
    }
}

// One block per (head-instance bh, 16-row Q tile). 4 waves.
// qkv: [8192][2304] bf16 (q at col h*64, k at 768+h*64, v at 1536+h*64)
// ctx: [8192][768] bf16
__global__ __launch_bounds__(256) void attn_kernel(const u16* __restrict__ qkv,
                                                   u16* __restrict__ ctx) {
  const int bh = blockIdx.x;
  const int b = bh / HEADS, h = bh % HEADS;
  const int qt = blockIdx.y;
  const int tid = threadIdx.x, wave = tid >> 6, lane = tid & 63;
  const int lr = lane & 15, g = lane >> 4, lk = g * 8;

  __shared__ u16 Qs[16 * 72];      // padded stride 72 -> 2-way conflicts only
  __shared__ u16 Ks[64 * 72];
  __shared__ u16 Vt[64 * 72];      // transposed V tile: Vt[e][k]
  __shared__ u16 Ps[16 * 1032];    // exp(S) in bf16, padded stride
  __shared__ float wsum[4][16];
  __shared__ float rowscale[16];

  const size_t tok0 = (size_t)b * SEQ;
  const int q0 = qt * 16;

  // Q tile -> LDS
  if (tid < 128) {
    int row = tid >> 3, seg = tid & 7;
    const u16* src = qkv + (tok0 + q0 + row) * TD + h * HDIM + seg * 8;
    *reinterpret_cast<uint4*>(&Qs[row * 72 + seg * 8]) = *reinterpret_cast<const uint4*>(src);
  }
  __syncthreads();

  bf16x8 qa[2];
  qa[0] = *reinterpret_cast<const bf16x8*>(&Qs[lr * 72 + lk]);
  qa[1] = *reinterpret_cast<const bf16x8*>(&Qs[lr * 72 + 32 + lk]);

  const int krow = tid >> 2, kseg = tid & 3;  // staging: 64 rows x 4 segs of 16

  // Phase 1: P = exp(Q K^T) (no max subtraction: |scores| <~ 15, safe in f32),
  // store bf16 P, accumulate row sums.
  float psum[4] = {0.f, 0.f, 0.f, 0.f};
  for (int kb = 0; kb < 16; ++kb) {
    {
      const u16* src = qkv + (tok0 + kb * 64 + krow) * TD + EMBED + h * HDIM + kseg * 16;
      *reinterpret_cast<uint4*>(&Ks[krow * 72 + kseg * 16])     = *reinterpret_cast<const uint4*>(src);
      *reinterpret_cast<uint4*>(&Ks[krow * 72 + kseg * 16 + 8]) = *reinterpret_cast<const uint4*>(src + 8);
    }
    __syncthreads();
    bf16x8 kf0 = *reinterpret_cast<const bf16x8*>(&Ks[(wave * 16 + lr) * 72 + lk]);
    bf16x8 kf1 = *reinterpret_cast<const bf16x8*>(&Ks[(wave * 16 + lr) * 72 + 32 + lk]);
    f32x4 s = 0.f;
    s = __builtin_amdgcn_mfma_f32_16x16x32_bf16(qa[0], kf0, s, 0, 0, 0);
    s = __builtin_amdgcn_mfma_f32_16x16x32_bf16(qa[1], kf1, s, 0, 0, 0);
    int col = kb * 64 + wave * 16 + lr;
#pragma unroll
    for (int j = 0; j < 4; ++j) {
      float e = __expf(s[j]);
      psum[j] += e;
      Ps[(g * 4 + j) * 1032 + col] = f2bf(e);
    }
    __syncthreads();
  }

  // row sums: reduce over the 16 lanes sharing group g, combine 4 waves via LDS
#pragma unroll
  for (int j = 0; j < 4; ++j) {
    float v = psum[j];
    v += __shfl_xor(v, 1); v += __shfl_xor(v, 2);
    v += __shfl_xor(v, 4); v += __shfl_xor(v, 8);
    if (lr == 0) wsum[wave][g * 4 + j] = v;
  }
  __syncthreads();
  if (tid < 16)
    rowscale[tid] = 0.125f / (wsum[0][tid] + wsum[1][tid] + wsum[2][tid] + wsum[3][tid]);
  __syncthreads();

  // Phase 3: O = P @ V ; wave w owns e-columns w*16..w*16+15
  f32x4 oacc = 0.f;
  for (int kb = 0; kb < 16; ++kb) {
    {
      const u16* src = qkv + (tok0 + kb * 64 + krow) * TD + 2 * EMBED + h * HDIM + kseg * 16;
      uint4 u0 = *reinterpret_cast<const uint4*>(src);
      uint4 u1 = *reinterpret_cast<const uint4*>(src + 8);
      u16 tmp[16];
      *reinterpret_cast<uint4*>(tmp)     = u0;
      *reinterpret_cast<uint4*>(tmp + 8) = u1;
#pragma unroll
      for (int i = 0; i < 16; ++i) Vt[(kseg * 16 + i) * 72 + krow] = tmp[i];
    }
    __syncthreads();
#pragma unroll
    for (int kk = 0; kk < 2; ++kk) {
      bf16x8 pa = *reinterpret_cast<const bf16x8*>(&Ps[lr * 1032 + kb * 64 + kk * 32 + lk]);
      bf16x8 vb = *reinterpret_cast<const bf16x8*>(&Vt[(wave * 16 + lr) * 72 + kk * 32 + lk]);
      oacc = __builtin_amdgcn_mfma_f32_16x16x32_bf16(pa, vb, oacc, 0, 0, 0);
    }
    __syncthreads();
  }

#pragma unroll
  for (int j = 0; j < 4; ++j) {
    int row = g * 4 + j;
    float v = oacc[j] * rowscale[row];
    ctx[(tok0 + q0 + row) * EMBED + h * HDIM + wave * 16 + lr] = f2bf(v);
  }
}

extern "C" void kernel_launch(void* const* d_in, const int* in_sizes, int n_in,
                              void* d_out, int out_size, void* d_ws, size_t ws_size,
                              hipStream_t stream) {
  (void)in_sizes; (void)n_in; (void)out_size;
  const float* x     = (const float*)d_in[0];
  const float* Wqkv  = (const float*)d_in[1];
  const float* bqkv  = (const float*)d_in[2];
  const float* Wproj = (const float*)d_in[3];
  const float* bproj = (const float*)d_in[4];
  float* out = (float*)d_out;

  char* ws = (char*)d_ws;
  size_t off = 0;
  auto alloc = [&](size_t bytes) {
    char* p = ws + off;
    off += (bytes + 255) & ~(size_t)255;
    return p;
  };
  u16* xb     = (u16*)alloc((size_t)MTOK * EMBED * 2);
  u16* wqkvb  = (u16*)alloc((size_t)TD * EMBED * 2);
  u16* wprojb = (u16*)alloc((size_t)EMBED * EMBED * 2);
  u16* qkvb   = (u16*)alloc((size_t)MTOK * TD * 2);
  u16* ctxb   = (u16*)alloc((size_t)MTOK * EMBED * 2);
  if (off > ws_size) return;  // workspace too small: leave output zero (loud failure)

  cast_kernel<<<dim3(1024), dim3(256), 0, stream>>>(x,     xb,     MTOK * EMBED / 4);
  cast_kernel<<<dim3(432),  dim3(256), 0, stream>>>(Wqkv,  wqkvb,  TD * EMBED / 4);
  cast_kernel<<<dim3(144),  dim3(256), 0, stream>>>(Wproj, wprojb, EMBED * EMBED / 4);

  // QKV projection: [8192,2304] = x @ Wqkv^T + b
  gemm_bt<true, true><<<dim3(64, 18), dim3(256), 0, stream>>>(xb, wqkvb, bqkv, qkvb, EMBED);
  // attention per (head, q-tile)
  attn_kernel<<<dim3(96, 64), dim3(256), 0, stream>>>(qkvb, ctxb);
  // output projection: out = ctx @ Wproj^T + b (f32 out)
  gemm_bt<false, true><<<dim3(64, 6), dim3(256), 0, stream>>>(ctxb, wprojb, bproj, out, EMBED);
}

// Round 2
// 137.321 us; speedup vs baseline: 2.4445x; 2.4445x over previous
//
#include <hip/hip_runtime.h>

typedef unsigned short u16;
typedef __attribute__((ext_vector_type(8))) short bf16x8;   // 8 bf16 (4 VGPRs)
typedef __attribute__((ext_vector_type(4))) float f32x4;

#define HEADS 12
#define HDIM  64
#define EMBED 768
#define TD    2304
#define SEQ   1024
#define MTOK  8192

// round-to-nearest-even f32 -> bf16
__device__ __forceinline__ u16 f2bf(float f) {
  union { float f; unsigned u; } x; x.f = f;
  unsigned r = x.u + 0x7fffu + ((x.u >> 16) & 1u);
  return (u16)(r >> 16);
}

__global__ void cast_kernel(const float* __restrict__ src, u16* __restrict__ dst, int n4) {
  int i = blockIdx.x * blockDim.x + threadIdx.x;
  int st = gridDim.x * blockDim.x;
  for (; i < n4; i += st) {
    float4 v = reinterpret_cast<const float4*>(src)[i];
    ushort4 o;
    o.x = f2bf(v.x); o.y = f2bf(v.y); o.z = f2bf(v.z); o.w = f2bf(v.w);
    reinterpret_cast<ushort4*>(dst)[i] = o;
  }
}

__device__ __forceinline__ void gload_lds16(const u16* g, u16* l) {
  __builtin_amdgcn_global_load_lds(
      (const __attribute__((address_space(1))) unsigned*)g,
      (__attribute__((address_space(3))) unsigned*)l, 16, 0, 0);
}

// C[M][N] = A[M][K] @ B[N][K]^T (+ bias[N]); A,B bf16; out bf16 or f32.
template <bool OUT_BF16, bool HAS_BIAS>
__global__ __launch_bounds__(256) void gemm_bt(const u16* __restrict__ A,
                                               const u16* __restrict__ B,
                                               const float* __restrict__ bias,
                                               void* __restrict__ Cv, int K) {
  __shared__ u16 As[128 * 32];
  __shared__ u16 Bs[128 * 32];
  const int tid  = threadIdx.x;
  const int wave = tid >> 6, lane = tid & 63;
  const int wr = wave >> 1, wc = wave & 1;
  const int lr = lane & 15, lk = (lane >> 4) * 8;
  const int Ndim = gridDim.y * 128;
  const int srow = lane >> 2;
  const int scol = (lane & 3) * 8;

  const u16* Ag = A + (size_t)(blockIdx.x * 128) * K;
  const u16* Bg = B + (size_t)(blockIdx.y * 128) * K;

  f32x4 acc[4][4];
#pragma unroll
  for (int m = 0; m < 4; ++m)
#pragma unroll
    for (int n = 0; n < 4; ++n) acc[m][n] = 0.f;

  for (int kt = 0; kt < K; kt += 32) {
#pragma unroll
    for (int c = 0; c < 2; ++c) {
      int slot = wave * 2 + c;
      int row  = slot * 16 + srow;
      gload_lds16(Ag + (size_t)row * K + kt + scol, &As[slot * 512]);
      gload_lds16(Bg + (size_t)row * K + kt + scol, &Bs[slot * 512]);
    }
    __syncthreads();
    bf16x8 af[4], bfr[4];
#pragma unroll
    for (int m = 0; m < 4; ++m)
      af[m] = *reinterpret_cast<const bf16x8*>(&As[(wr * 64 + m * 16 + lr) * 32 + lk]);
#pragma unroll
    for (int n = 0; n < 4; ++n)
      bfr[n] = *reinterpret_cast<const bf16x8*>(&Bs[(wc * 64 + n * 16 + lr) * 32 + lk]);
#pragma unroll
    for (int m = 0; m < 4; ++m)
#pragma unroll
      for (int n = 0; n < 4; ++n)
        acc[m][n] = __builtin_amdgcn_mfma_f32_16x16x32_bf16(af[m], bfr[n], acc[m][n], 0, 0, 0);
    __syncthreads();
  }

  const int row0 = blockIdx.x * 128 + wr * 64 + (lane >> 4) * 4;
  const int col0 = blockIdx.y * 128 + wc * 64 + lr;
#pragma unroll
  for (int m = 0; m < 4; ++m)
#pragma unroll
    for (int n = 0; n < 4; ++n) {
      int col = col0 + n * 16;
      float bv = HAS_BIAS ? bias[col] : 0.f;
#pragma unroll
      for (int j = 0; j < 4; ++j) {
        int row = row0 + m * 16 + j;
        float v = acc[m][n][j] + bv;
        if (OUT_BF16) ((u16*)Cv)[(size_t)row * Ndim + col] = f2bf(v);
        else          ((float*)Cv)[(size_t)row * Ndim + col] = v;
      }
    }
}

// Transpose V region of qkv into vt[bh][e][tok] (bf16).
__global__ __launch_bounds__(256) void vtrans_kernel(const u16* __restrict__ qkv,
                                                     u16* __restrict__ vt) {
  const int bh = blockIdx.x, kb = blockIdx.y;
  const int b = bh / HEADS, h = bh % HEADS;
  __shared__ u16 Ls[64 * 72];
  const int t = threadIdx.x;
  const int row = t >> 2, seg = t & 3;
  const u16* src = qkv + (size_t)(b * SEQ + kb * 64 + row) * TD + 2 * EMBED + h * HDIM + seg * 16;
  *reinterpret_cast<uint4*>(&Ls[row * 72 + seg * 16])     = *reinterpret_cast<const uint4*>(src);
  *reinterpret_cast<uint4*>(&Ls[row * 72 + seg * 16 + 8]) = *reinterpret_cast<const uint4*>(src + 8);
  __syncthreads();
  u16 tmp[16];
#pragma unroll
  for (int i = 0; i < 16; ++i) tmp[i] = Ls[(seg * 16 + i) * 72 + row];
  u16* dst = vt + (size_t)bh * (HDIM * SEQ) + (size_t)row * SEQ + kb * 64 + seg * 16;
  *reinterpret_cast<uint4*>(dst)     = *reinterpret_cast<const uint4*>(tmp);
  *reinterpret_cast<uint4*>(dst + 8) = *reinterpret_cast<const uint4*>(tmp + 8);
}

// Fused attention: block = (head-instance bh, 128-row Q tile), 4 waves.
// Wave w owns q-rows [w*32, w*32+32). Swapped QK^T (mfma(K,Q) -> S^T) makes
// P k-consecutive per lane -> vectorized LDS writes; P is wave-private.
__global__ __launch_bounds__(256) void attn_kernel(const u16* __restrict__ qkv,
                                                   const u16* __restrict__ vt,
                                                   u16* __restrict__ ctx) {
  const int bh = blockIdx.x;
  const int b = bh / HEADS, h = bh % HEADS;
  const int qt = blockIdx.y;
  const int tid = threadIdx.x, wave = tid >> 6, lane = tid & 63;
  const int lr = lane & 15, g = lane >> 4;

  __shared__ u16 Ks[64 * 64];   // [k-row][d], 16B chunks XOR-swizzled by row&7
  __shared__ u16 Vs[64 * 64];   // [e][k] (pre-transposed), same swizzle
  __shared__ u16 Ps[128 * 64];  // [m][k], 8B granules swizzled by (m&7)<<1

  const size_t tok0 = (size_t)b * SEQ;
  const int q0 = qt * 128;
  const int mbase = wave * 32;

  // Q fragments (B operand of swapped QK^T): rows mbase+{0,16}+lr, d in 2 halves
  bf16x8 qf[2][2];
#pragma unroll
  for (int mi = 0; mi < 2; ++mi)
#pragma unroll
    for (int dk = 0; dk < 2; ++dk)
      qf[mi][dk] = *reinterpret_cast<const bf16x8*>(
          qkv + (tok0 + q0 + mbase + mi * 16 + lr) * TD + h * HDIM + dk * 32 + g * 8);

  const int srow = lane >> 3;                 // row within 8-row staging chunk
  const int schunk = (lane & 7) ^ srow;       // pre-swizzled global 16B-chunk

  f32x4 oacc[2][4];
#pragma unroll
  for (int mi = 0; mi < 2; ++mi)
#pragma unroll
    for (int e = 0; e < 4; ++e) oacc[mi][e] = 0.f;
  float psum[2] = {0.f, 0.f};

  for (int kb = 0; kb < 16; ++kb) {
#pragma unroll
    for (int c2 = 0; c2 < 2; ++c2) {
      int call = wave * 2 + c2;               // 0..7
      int row  = call * 8 + srow;
      gload_lds16(qkv + (tok0 + kb * 64 + row) * TD + EMBED + h * HDIM + schunk * 8,
                  &Ks[call * 512]);
      gload_lds16(vt + (size_t)bh * (HDIM * SEQ) + (size_t)row * SEQ + kb * 64 + schunk * 8,
                  &Vs[call * 512]);
    }
    __syncthreads();

    // S^T = K @ Q^T : A-frags = K rows (shared), B-frags = Q (regs)
    bf16x8 ka[4][2];
#pragma unroll
    for (int n = 0; n < 4; ++n)
#pragma unroll
      for (int dk = 0; dk < 2; ++dk) {
        int r = n * 16 + lr;
        int c = dk * 4 + g;
        ka[n][dk] = *reinterpret_cast<const bf16x8*>(&Ks[r * 64 + ((c ^ (r & 7)) << 3)]);
      }
#pragma unroll
    for (int mi = 0; mi < 2; ++mi) {
      int m = mbase + mi * 16 + lr;
      int pswz = (lr & 7) << 1;
#pragma unroll
      for (int n = 0; n < 4; ++n) {
        f32x4 s = 0.f;
        s = __builtin_amdgcn_mfma_f32_16x16x32_bf16(ka[n][0], qf[mi][0], s, 0, 0, 0);
        s = __builtin_amdgcn_mfma_f32_16x16x32_bf16(ka[n][1], qf[mi][1], s, 0, 0, 0);
        float e0 = __expf(s[0]), e1 = __expf(s[1]);
        float e2 = __expf(s[2]), e3 = __expf(s[3]);
        psum[mi] += (e0 + e1) + (e2 + e3);
        ushort4 pw;
        pw.x = f2bf(e0); pw.y = f2bf(e1); pw.z = f2bf(e2); pw.w = f2bf(e3);
        int gran = n * 4 + g;                 // k-granule (4 elems) 0..15
        *reinterpret_cast<ushort4*>(&Ps[m * 64 + ((gran ^ pswz) << 2)]) = pw;
      }
    }

    // O += P @ V : A = P (wave-private, no barrier needed), B = Vt
    bf16x8 vb2[4][2];
#pragma unroll
    for (int e = 0; e < 4; ++e)
#pragma unroll
      for (int kk = 0; kk < 2; ++kk) {
        int r = e * 16 + lr;
        int c = kk * 4 + g;
        vb2[e][kk] = *reinterpret_cast<const bf16x8*>(&Vs[r * 64 + ((c ^ (r & 7)) << 3)]);
      }
#pragma unroll
    for (int mi = 0; mi < 2; ++mi) {
      bf16x8 pa[2];
#pragma unroll
      for (int kk = 0; kk < 2; ++kk) {
        int r = mbase + mi * 16 + lr;
        int c = kk * 4 + g;
        pa[kk] = *reinterpret_cast<const bf16x8*>(&Ps[r * 64 + ((c ^ (r & 7)) << 3)]);
      }
#pragma unroll
      for (int e = 0; e < 4; ++e) {
        oacc[mi][e] = __builtin_amdgcn_mfma_f32_16x16x32_bf16(pa[0], vb2[e][0], oacc[mi][e], 0, 0, 0);
        oacc[mi][e] = __builtin_amdgcn_mfma_f32_16x16x32_bf16(pa[1], vb2[e][1], oacc[mi][e], 0, 0, 0);
      }
    }
    __syncthreads();
  }

  // denominators: wave-local reduce across the 4 lane-groups
  float scl[2][4];
#pragma unroll
  for (int mi = 0; mi < 2; ++mi) {
    float v = psum[mi];
    v += __shfl_xor(v, 16);
    v += __shfl_xor(v, 32);
    v = 0.125f / v;                           // post-softmax scaling folded in
#pragma unroll
    for (int j = 0; j < 4; ++j) scl[mi][j] = __shfl(v, 4 * g + j);
  }
#pragma unroll
  for (int mi = 0; mi < 2; ++mi)
#pragma unroll
    for (int e = 0; e < 4; ++e)
#pragma unroll
      for (int j = 0; j < 4; ++j) {
        float v = oacc[mi][e][j] * scl[mi][j];
        ctx[(tok0 + q0 + mbase + mi * 16 + 4 * g + j) * EMBED + h * HDIM + e * 16 + lr] = f2bf(v);
      }
}

extern "C" void kernel_launch(void* const* d_in, const int* in_sizes, int n_in,
                              void* d_out, int out_size, void* d_ws, size_t ws_size,
                              hipStream_t stream) {
  (void)in_sizes; (void)n_in; (void)out_size;
  const float* x     = (const float*)d_in[0];
  const float* Wqkv  = (const float*)d_in[1];
  const float* bqkv  = (const float*)d_in[2];
  const float* Wproj = (const float*)d_in[3];
  const float* bproj = (const float*)d_in[4];
  float* out = (float*)d_out;

  char* ws = (char*)d_ws;
  size_t off = 0;
  auto alloc = [&](size_t bytes) {
    char* p = ws + off;
    off += (bytes + 255) & ~(size_t)255;
    return p;
  };
  u16* xb     = (u16*)alloc((size_t)MTOK * EMBED * 2);
  u16* wqkvb  = (u16*)alloc((size_t)TD * EMBED * 2);
  u16* wprojb = (u16*)alloc((size_t)EMBED * EMBED * 2);
  u16* qkvb   = (u16*)alloc((size_t)MTOK * TD * 2);
  u16* ctxb   = (u16*)alloc((size_t)MTOK * EMBED * 2);
  if (off > ws_size) return;  // workspace too small: loud failure
  u16* vtb = xb;  // reuse: xb is dead after the QKV GEMM; vt is same size

  cast_kernel<<<dim3(1024), dim3(256), 0, stream>>>(x,     xb,     MTOK * EMBED / 4);
  cast_kernel<<<dim3(432),  dim3(256), 0, stream>>>(Wqkv,  wqkvb,  TD * EMBED / 4);
  cast_kernel<<<dim3(144),  dim3(256), 0, stream>>>(Wproj, wprojb, EMBED * EMBED / 4);

  // QKV projection: [8192,2304] = x @ Wqkv^T + b
  gemm_bt<true, true><<<dim3(64, 18), dim3(256), 0, stream>>>(xb, wqkvb, bqkv, qkvb, EMBED);
  // V transpose into vt[bh][e][tok] (aliases xb)
  vtrans_kernel<<<dim3(96, 16), dim3(256), 0, stream>>>(qkvb, vtb);
  // fused attention
  attn_kernel<<<dim3(96, 8), dim3(256), 0, stream>>>(qkvb, vtb, ctxb);
  // output projection: out = ctx @ Wproj^T + b (f32 out)
  gemm_bt<false, true><<<dim3(64, 6), dim3(256), 0, stream>>>(ctxb, wprojb, bproj, out, EMBED);
}